// Round 12
// baseline (244.772 us; speedup 1.0000x reference)
//
#include <hip/hip_runtime.h>

using f16x8 = _Float16 __attribute__((ext_vector_type(8)));
using f32x4 = float __attribute__((ext_vector_type(4)));

#define BS      8192
#define IN_DIM  4096
#define NB      64
#define BD      64
#define HID     256
#define OD      64
#define GYP     8          // 8 y-groups x (16 waves x 32 rows x 2 slabs) = 8192 rows
#define SLABS   2

__device__ __forceinline__ float gelu_f(float z) {
    // x*sigmoid(1.702x): exp(-1.702 z) = exp2(-2.4554443 z)
    float e = __builtin_amdgcn_exp2f(z * -2.4554443f);
    float r = __builtin_amdgcn_rcpf(e + 1.0f);
    return z * r;
}

// ---- prep: build fragment-major f16 weight images in d_ws (once per launch).
__global__ __launch_bounds__(256) void prep_weights(
    const float* __restrict__ w1g, const float* __restrict__ w2g,
    f16x8* __restrict__ ws1, f16x8* __restrict__ ws2) {
    const int n = blockIdx.x;
    const int t = threadIdx.x;
    const float* W1n = w1g + (size_t)n * (BD * HID);
    const float* W2n = w2g + (size_t)n * (HID * OD);
    #pragma unroll
    for (int it = 0; it < 8; ++it) {
        int e = it * 256 + t;
        {
            int ht = e >> 7, ks = (e >> 6) & 1, le = e & 63;
            int ge = le >> 4, oo = le & 15;
            f16x8 v;
            #pragma unroll
            for (int j = 0; j < 8; ++j)
                v[j] = (_Float16)W1n[(size_t)(ks * 32 + ge * 8 + j) * HID + ht * 16 + oo];
            ws1[(size_t)n * 2048 + e] = v;
        }
        {
            int p = e >> 8, n2 = (e >> 6) & 3, le = e & 63;
            int ge = le >> 4, ce = le & 15;
            f16x8 v;
            #pragma unroll
            for (int j = 0; j < 8; ++j)
                v[j] = (_Float16)W2n[(size_t)(p * 32 + ((j >> 2) << 4) + ge * 4 + (j & 3)) * OD + n2 * 16 + ce];
            ws2[(size_t)n * 2048 + e] = v;
        }
    }
}

// 1024-thread WGs: 2 WGs/CU (130 KB LDS) x 16 waves = 32 waves/CU — the full
// occupancy cap. Requires VGPR <= 64: launch_bounds(1024,8) pins the cap;
// this body compiled to 60 VGPR under (512,4) in R8.
__global__ __launch_bounds__(1024, 8) void blockmlp_kernel(
    const float* __restrict__ xg,
    const f16x8* __restrict__ ws1, const f16x8* __restrict__ ws2,
    const float* __restrict__ b1g, const float* __restrict__ b2g,
    float* __restrict__ outg) {

    __shared__ f16x8 W1F[2048];   // 32 KB  [ht=16][ks=2][lane]
    __shared__ f16x8 W2L[2048];   // 32 KB  [p=8][n2=4][lane]
    __shared__ float b1L[HID];    // 1 KB

    const int tid = threadIdx.x;
    const int w   = tid >> 6;    // 0..15
    const int l   = tid & 63;
    const int g   = l >> 4;
    const int l15 = l & 15;
    const int n   = blockIdx.x;

    // ---- stage prebuilt fragments (coalesced b128 loads + b128 LDS writes)
    const f16x8* p1 = ws1 + (size_t)n * 2048;
    const f16x8* p2 = ws2 + (size_t)n * 2048;
    f16x8 s1[2], s2[2];
    #pragma unroll
    for (int it = 0; it < 2; ++it) { s1[it] = p1[it * 1024 + tid]; }
    #pragma unroll
    for (int it = 0; it < 2; ++it) { s2[it] = p2[it * 1024 + tid]; }
    #pragma unroll
    for (int it = 0; it < 2; ++it) { W1F[it * 1024 + tid] = s1[it]; }
    #pragma unroll
    for (int it = 0; it < 2; ++it) { W2L[it * 1024 + tid] = s2[it]; }

    if (tid < HID) b1L[tid] = b1g[n * HID + tid];

    float b2b[4];
    #pragma unroll
    for (int n2 = 0; n2 < 4; ++n2) b2b[n2] = b2g[n * OD + n2 * 16 + l15];

    __syncthreads();   // only barrier

    const int base = blockIdx.y * (SLABS * 512) + w * 32;

    #pragma unroll
    for (int s = 0; s < SLABS; ++s) {
        const int row0 = base + s * 512;

        // ---- x fragments (B-op of swapped GEMM1): x[row0+rs*16+l15][k=ks*32+g*8+j]
        f16x8 xa[2][2];
        #pragma unroll
        for (int rs = 0; rs < 2; ++rs)
            #pragma unroll
            for (int ks = 0; ks < 2; ++ks) {
                const float* px = xg + (size_t)(row0 + rs * 16 + l15) * IN_DIM + n * BD + ks * 32 + g * 8;
                float4 lo = *(const float4*)px;
                float4 hi = *(const float4*)(px + 4);
                f16x8 v;
                v[0] = (_Float16)lo.x; v[1] = (_Float16)lo.y;
                v[2] = (_Float16)lo.z; v[3] = (_Float16)lo.w;
                v[4] = (_Float16)hi.x; v[5] = (_Float16)hi.y;
                v[6] = (_Float16)hi.z; v[7] = (_Float16)hi.w;
                xa[rs][ks] = v;
            }

        // c2 initialized to the layer-2 bias
        f32x4 c2[2][4];
        #pragma unroll
        for (int rs = 0; rs < 2; ++rs)
            #pragma unroll
            for (int n2 = 0; n2 < 4; ++n2) {
                f32x4 ci;
                ci[0] = b2b[n2]; ci[1] = b2b[n2]; ci[2] = b2b[n2]; ci[3] = b2b[n2];
                c2[rs][n2] = ci;
            }

        #pragma unroll
        for (int p = 0; p < 8; ++p) {
            // GEMM1 (swapped), b1 folded into C-init
            f32x4 c1[2][2];   // [htl][rs]
            #pragma unroll
            for (int htl = 0; htl < 2; ++htl) {
                f32x4 cb = *(const f32x4*)&b1L[(p * 2 + htl) * 16 + g * 4];
                c1[htl][0] = cb; c1[htl][1] = cb;
                #pragma unroll
                for (int ks = 0; ks < 2; ++ks) {
                    f16x8 wf = W1F[(((p * 2 + htl) * 2) + ks) * 64 + l];
                    c1[htl][0] = __builtin_amdgcn_mfma_f32_16x16x32_f16(wf, xa[0][ks], c1[htl][0], 0, 0, 0);
                    c1[htl][1] = __builtin_amdgcn_mfma_f32_16x16x32_f16(wf, xa[1][ks], c1[htl][1], 0, 0, 0);
                }
            }
            // gelu in registers -> A2 fragments (k2-map by construction)
            f16x8 a2[2];
            #pragma unroll
            for (int rs = 0; rs < 2; ++rs) {
                f16x8 v;
                #pragma unroll
                for (int q = 0; q < 4; ++q) {
                    v[q]     = (_Float16)gelu_f(c1[0][rs][q]);
                    v[q + 4] = (_Float16)gelu_f(c1[1][rs][q]);
                }
                a2[rs] = v;
            }
            // GEMM2 partial: K-slice p*32..p*32+31
            #pragma unroll
            for (int n2 = 0; n2 < 4; ++n2) {
                f16x8 bf = W2L[(p * 4 + n2) * 64 + l];
                c2[0][n2] = __builtin_amdgcn_mfma_f32_16x16x32_f16(a2[0], bf, c2[0][n2], 0, 0, 0);
                c2[1][n2] = __builtin_amdgcn_mfma_f32_16x16x32_f16(a2[1], bf, c2[1][n2], 0, 0, 0);
            }
        }

        // ---- epilogue: fp32 store (bias already in c2), R8 order
        #pragma unroll
        for (int rs = 0; rs < 2; ++rs)
            #pragma unroll
            for (int n2 = 0; n2 < 4; ++n2)
                #pragma unroll
                for (int q = 0; q < 4; ++q) {
                    int row = row0 + rs * 16 + g * 4 + q;
                    outg[(size_t)row * IN_DIM + n * BD + n2 * 16 + l15] = c2[rs][n2][q];
                }
    }
}

extern "C" void kernel_launch(void* const* d_in, const int* in_sizes, int n_in,
                              void* d_out, int out_size, void* d_ws, size_t ws_size,
                              hipStream_t stream) {
    const float* x  = (const float*)d_in[0];
    const float* W1 = (const float*)d_in[1];
    const float* b1 = (const float*)d_in[2];
    const float* W2 = (const float*)d_in[3];
    const float* b2 = (const float*)d_in[4];
    float* out = (float*)d_out;

    f16x8* ws1 = (f16x8*)d_ws;            // 64*2048*16 B = 2 MB
    f16x8* ws2 = ws1 + (size_t)NB * 2048; // +2 MB  (ws_size must be >= 4 MB)

    hipLaunchKernelGGL(prep_weights, dim3(NB), dim3(256), 0, stream, W1, W2, ws1, ws2);
    hipLaunchKernelGGL(blockmlp_kernel, dim3(NB, GYP), dim3(1024), 0, stream,
                       x, ws1, ws2, b1, b2, out);
}

// Round 13
// 87.137 us; speedup vs baseline: 2.8090x; 2.8090x over previous
//
#include <hip/hip_runtime.h>

using f16x8 = _Float16 __attribute__((ext_vector_type(8)));
using f32x4 = float __attribute__((ext_vector_type(4)));

#define BS      8192
#define IN_DIM  4096
#define NB      64
#define BD      64
#define HID     256
#define OD      64
#define GYP     8          // 8 y-groups x (8 waves x 32 rows x 4 slabs) = 8192 rows
#define SLABS   4

__device__ __forceinline__ float gelu_f(float z) {
    // x*sigmoid(1.702x): exp(-1.702 z) = exp2(-2.4554443 z)
    float e = __builtin_amdgcn_exp2f(z * -2.4554443f);
    float r = __builtin_amdgcn_rcpf(e + 1.0f);
    return z * r;
}

// ---- prep: build fragment-major f16 weight images in d_ws (once per launch).
__global__ __launch_bounds__(256) void prep_weights(
    const float* __restrict__ w1g, const float* __restrict__ w2g,
    f16x8* __restrict__ ws1, f16x8* __restrict__ ws2) {
    const int n = blockIdx.x;
    const int t = threadIdx.x;
    const float* W1n = w1g + (size_t)n * (BD * HID);
    const float* W2n = w2g + (size_t)n * (HID * OD);
    #pragma unroll
    for (int it = 0; it < 8; ++it) {
        int e = it * 256 + t;
        {
            int ht = e >> 7, ks = (e >> 6) & 1, le = e & 63;
            int ge = le >> 4, oo = le & 15;
            f16x8 v;
            #pragma unroll
            for (int j = 0; j < 8; ++j)
                v[j] = (_Float16)W1n[(size_t)(ks * 32 + ge * 8 + j) * HID + ht * 16 + oo];
            ws1[(size_t)n * 2048 + e] = v;
        }
        {
            int p = e >> 8, n2 = (e >> 6) & 3, le = e & 63;
            int ge = le >> 4, ce = le & 15;
            f16x8 v;
            #pragma unroll
            for (int j = 0; j < 8; ++j)
                v[j] = (_Float16)W2n[(size_t)(p * 32 + ((j >> 2) << 4) + ge * 4 + (j & 3)) * OD + n2 * 16 + ce];
            ws2[(size_t)n * 2048 + e] = v;
        }
    }
}

// R8 body verbatim; ONLY change: grid axes swapped so dispatch id = y + 8*n.
// XCD = id % 8 = y % 8 -> each XCD owns a contiguous 1024-row span across ALL
// 64 blocks: its DRAM stream is whole 16-KB rows instead of 64 interleaved
// 4-KB-strided 256-B column slices. (T1 XCD-locality mechanism.)
__global__ __launch_bounds__(512, 4) void blockmlp_kernel(
    const float* __restrict__ xg,
    const f16x8* __restrict__ ws1, const f16x8* __restrict__ ws2,
    const float* __restrict__ b1g, const float* __restrict__ b2g,
    float* __restrict__ outg) {

    __shared__ f16x8 W1F[2048];   // 32 KB  [ht=16][ks=2][lane]
    __shared__ f16x8 W2L[2048];   // 32 KB  [p=8][n2=4][lane]
    __shared__ float b1L[HID];    // 1 KB

    const int tid = threadIdx.x;
    const int w   = tid >> 6;
    const int l   = tid & 63;
    const int g   = l >> 4;
    const int l15 = l & 15;
    const int n   = blockIdx.y;   // block index (was blockIdx.x)

    // ---- stage prebuilt fragments (coalesced b128 loads + b128 LDS writes)
    const f16x8* p1 = ws1 + (size_t)n * 2048;
    const f16x8* p2 = ws2 + (size_t)n * 2048;
    f16x8 s1[4], s2[4];
    #pragma unroll
    for (int it = 0; it < 4; ++it) { s1[it] = p1[it * 512 + tid]; }
    #pragma unroll
    for (int it = 0; it < 4; ++it) { s2[it] = p2[it * 512 + tid]; }
    #pragma unroll
    for (int it = 0; it < 4; ++it) { W1F[it * 512 + tid] = s1[it]; }
    #pragma unroll
    for (int it = 0; it < 4; ++it) { W2L[it * 512 + tid] = s2[it]; }

    if (tid < HID) b1L[tid] = b1g[n * HID + tid];

    float b2b[4];
    #pragma unroll
    for (int n2 = 0; n2 < 4; ++n2) b2b[n2] = b2g[n * OD + n2 * 16 + l15];

    __syncthreads();   // only barrier

    const int base = blockIdx.x * (SLABS * 256) + w * 32;

    #pragma unroll
    for (int s = 0; s < SLABS; ++s) {
        const int row0 = base + s * 256;

        // ---- x fragments (B-op of swapped GEMM1): x[row0+rs*16+l15][k=ks*32+g*8+j]
        f16x8 xa[2][2];
        #pragma unroll
        for (int rs = 0; rs < 2; ++rs)
            #pragma unroll
            for (int ks = 0; ks < 2; ++ks) {
                const float* px = xg + (size_t)(row0 + rs * 16 + l15) * IN_DIM + n * BD + ks * 32 + g * 8;
                float4 lo = *(const float4*)px;
                float4 hi = *(const float4*)(px + 4);
                f16x8 v;
                v[0] = (_Float16)lo.x; v[1] = (_Float16)lo.y;
                v[2] = (_Float16)lo.z; v[3] = (_Float16)lo.w;
                v[4] = (_Float16)hi.x; v[5] = (_Float16)hi.y;
                v[6] = (_Float16)hi.z; v[7] = (_Float16)hi.w;
                xa[rs][ks] = v;
            }

        // c2 initialized to the layer-2 bias
        f32x4 c2[2][4];
        #pragma unroll
        for (int rs = 0; rs < 2; ++rs)
            #pragma unroll
            for (int n2 = 0; n2 < 4; ++n2) {
                f32x4 ci;
                ci[0] = b2b[n2]; ci[1] = b2b[n2]; ci[2] = b2b[n2]; ci[3] = b2b[n2];
                c2[rs][n2] = ci;
            }

        #pragma unroll
        for (int p = 0; p < 8; ++p) {
            // GEMM1 (swapped), b1 folded into C-init
            f32x4 c1[2][2];   // [htl][rs]
            #pragma unroll
            for (int htl = 0; htl < 2; ++htl) {
                f32x4 cb = *(const f32x4*)&b1L[(p * 2 + htl) * 16 + g * 4];
                c1[htl][0] = cb; c1[htl][1] = cb;
                #pragma unroll
                for (int ks = 0; ks < 2; ++ks) {
                    f16x8 wf = W1F[(((p * 2 + htl) * 2) + ks) * 64 + l];
                    c1[htl][0] = __builtin_amdgcn_mfma_f32_16x16x32_f16(wf, xa[0][ks], c1[htl][0], 0, 0, 0);
                    c1[htl][1] = __builtin_amdgcn_mfma_f32_16x16x32_f16(wf, xa[1][ks], c1[htl][1], 0, 0, 0);
                }
            }
            // gelu in registers -> A2 fragments (k2-map by construction)
            f16x8 a2[2];
            #pragma unroll
            for (int rs = 0; rs < 2; ++rs) {
                f16x8 v;
                #pragma unroll
                for (int q = 0; q < 4; ++q) {
                    v[q]     = (_Float16)gelu_f(c1[0][rs][q]);
                    v[q + 4] = (_Float16)gelu_f(c1[1][rs][q]);
                }
                a2[rs] = v;
            }
            // GEMM2 partial: K-slice p*32..p*32+31
            #pragma unroll
            for (int n2 = 0; n2 < 4; ++n2) {
                f16x8 bf = W2L[(p * 4 + n2) * 64 + l];
                c2[0][n2] = __builtin_amdgcn_mfma_f32_16x16x32_f16(a2[0], bf, c2[0][n2], 0, 0, 0);
                c2[1][n2] = __builtin_amdgcn_mfma_f32_16x16x32_f16(a2[1], bf, c2[1][n2], 0, 0, 0);
            }
        }

        // ---- epilogue: fp32 store (bias already in c2)
        #pragma unroll
        for (int rs = 0; rs < 2; ++rs)
            #pragma unroll
            for (int n2 = 0; n2 < 4; ++n2)
                #pragma unroll
                for (int q = 0; q < 4; ++q) {
                    int row = row0 + rs * 16 + g * 4 + q;
                    outg[(size_t)row * IN_DIM + n * BD + n2 * 16 + l15] = c2[rs][n2][q];
                }
    }
}

extern "C" void kernel_launch(void* const* d_in, const int* in_sizes, int n_in,
                              void* d_out, int out_size, void* d_ws, size_t ws_size,
                              hipStream_t stream) {
    const float* x  = (const float*)d_in[0];
    const float* W1 = (const float*)d_in[1];
    const float* b1 = (const float*)d_in[2];
    const float* W2 = (const float*)d_in[3];
    const float* b2 = (const float*)d_in[4];
    float* out = (float*)d_out;

    f16x8* ws1 = (f16x8*)d_ws;            // 64*2048*16 B = 2 MB
    f16x8* ws2 = ws1 + (size_t)NB * 2048; // +2 MB  (ws_size must be >= 4 MB)

    hipLaunchKernelGGL(prep_weights, dim3(NB), dim3(256), 0, stream, W1, W2, ws1, ws2);
    // grid axes swapped: x = y-group (8), y = block n (64) -> id = y + 8*n
    hipLaunchKernelGGL(blockmlp_kernel, dim3(GYP, NB), dim3(512), 0, stream,
                       x, ws1, ws2, b1, b2, out);
}